// Round 10
// baseline (873.744 us; speedup 1.0000x reference)
//
#include <hip/hip_runtime.h>
#include <hip/hip_bf16.h>
#include <cstdint>
#include <cstddef>

typedef float  f32x4  __attribute__((ext_vector_type(4)));
typedef __bf16 bf16x8 __attribute__((ext_vector_type(8)));
typedef __bf16 bf16x4 __attribute__((ext_vector_type(4)));

#define N_TOK  8192
#define INDIM  1024
#define DMODEL 512
#define SPLIT  2
#define KEYS_PER (N_TOK / SPLIT)   // 4096

__device__ __forceinline__ f32x4 mfma16x16x32(bf16x8 a, bf16x8 b, f32x4 c){
  return __builtin_amdgcn_mfma_f32_16x16x32_bf16(a, b, c, 0, 0, 0);
}

__device__ __forceinline__ void async_copy16(void* lds, const void* g){
  __builtin_amdgcn_global_load_lds((__attribute__((address_space(1))) void*)g,
                                   (__attribute__((address_space(3))) void*)lds,
                                   16, 0, 0);
}

// ---------------- convert / transpose ----------------
__global__ void k_cvt(const float* __restrict__ in, __bf16* __restrict__ out, int n4){
  int stride = gridDim.x * blockDim.x;
  for (int i = blockIdx.x * blockDim.x + threadIdx.x; i < n4; i += stride){
    f32x4 v = ((const f32x4*)in)[i];
    bf16x4 o;
    o[0]=(__bf16)v[0]; o[1]=(__bf16)v[1]; o[2]=(__bf16)v[2]; o[3]=(__bf16)v[3];
    ((bf16x4*)out)[i] = o;
  }
}

__global__ void k_tcvt(const float* __restrict__ W, __bf16* __restrict__ Wt, int Kd, int Nd){
  int total = Kd * Nd;
  int stride = gridDim.x * blockDim.x;
  for (int i = blockIdx.x * blockDim.x + threadIdx.x; i < total; i += stride){
    int k = i / Nd, n = i - k * Nd;
    Wt[(size_t)n * Kd + k] = (__bf16)W[i];
  }
}

// ---------------- GEMM: C[M,N] = A[M,K] @ Bt[N,K]^T + bias ----------------
template<int BIAS_ROW>
__global__ __launch_bounds__(256) void k_gemm_bt(
    const __bf16* __restrict__ A, const __bf16* __restrict__ Bt,
    const float* __restrict__ bias, __bf16* __restrict__ C,
    int M, int N, int K)
{
  __shared__ __bf16 Als[128][32];
  __shared__ __bf16 Bls[128][32];
  const int tid = threadIdx.x;
  const int w = tid >> 6, l = tid & 63;
  const int lr = l & 15, lg = l >> 4;
  const int wr = w >> 1, wc = w & 1;
  const int m0 = blockIdx.x * 128, n0 = blockIdx.y * 128;
  const int srow = l >> 2;
  const int skof = (l & 3) * 8;
  f32x4 acc[4][4] = {};
  for (int k0 = 0; k0 < K; k0 += 32){
    #pragma unroll
    for (int i = 0; i < 2; ++i){
      int c = i * 4 + w;
      async_copy16((char*)&Als[0][0] + c * 1024,
                   A  + (size_t)(m0 + c*16 + srow) * K + k0 + skof);
      async_copy16((char*)&Bls[0][0] + c * 1024,
                   Bt + (size_t)(n0 + c*16 + srow) * K + k0 + skof);
    }
    __syncthreads();
    bf16x8 af[4], bfv[4];
    #pragma unroll
    for (int mf = 0; mf < 4; ++mf) af[mf]  = *(const bf16x8*)&Als[wr*64 + mf*16 + lr][lg*8];
    #pragma unroll
    for (int nf = 0; nf < 4; ++nf) bfv[nf] = *(const bf16x8*)&Bls[wc*64 + nf*16 + lr][lg*8];
    #pragma unroll
    for (int mf = 0; mf < 4; ++mf)
      #pragma unroll
      for (int nf = 0; nf < 4; ++nf)
        acc[mf][nf] = mfma16x16x32(af[mf], bfv[nf], acc[mf][nf]);
    __syncthreads();
  }
  #pragma unroll
  for (int mf = 0; mf < 4; ++mf)
    #pragma unroll
    for (int nf = 0; nf < 4; ++nf)
      #pragma unroll
      for (int r = 0; r < 4; ++r){
        int row = m0 + wr*64 + mf*16 + lg*4 + r;
        int col = n0 + wc*64 + nf*16 + lr;
        float v = acc[mf][nf][r] + (BIAS_ROW ? bias[row] : bias[col]);
        C[(size_t)row * N + col] = (__bf16)v;
      }
}

// ---------------- flash attention v10 = R3 + K-reg prefetch-ahead ----------
// BQ=64, BK=64, SPLIT=2, 256 blocks (1/CU), 8 waves. Identical to the 377us
// R3 kernel except: the wave's 16 K-fragments live in registers, single-
// buffered, refilled for iter t+1 right after QK(t) consumes them -> the
// refill drains under softmax+PV+barriers (~5K cy) and QK never stalls on L2.
__global__ __launch_bounds__(512, 2) void k_flash(
    const __bf16* __restrict__ Qm, const __bf16* __restrict__ Km,
    const __bf16* __restrict__ Vt, __bf16* __restrict__ O0,
    __bf16* __restrict__ O1, float* __restrict__ mA, float* __restrict__ lA)
{
  __shared__ float  SP[2*64*64];    // 32 KB
  __shared__ __bf16 Pls[64*64];     // 8 KB
  __shared__ float  mls[64], lls[64], fls[64];
  const int tid = threadIdx.x;
  const int w = tid >> 6, l = tid & 63;
  const int lr = l & 15, lg = l >> 4;
  const int q0 = blockIdx.x * 64;
  const int sp = blockIdx.y;
  const int kbase = sp * KEYS_PER;
  const int mf2 = w & 1, nf2 = (w >> 1) & 1, dh = w >> 2;
  const int d0 = w * 64;
  // Q fragments: 2 strips (within mf2 half) x 8 K-chunks of D-half dh
  bf16x8 qf[2][8];
  #pragma unroll
  for (int st = 0; st < 2; ++st)
    #pragma unroll
    for (int tt = 0; tt < 8; ++tt)
      qf[st][tt] = *(const bf16x8*)&Qm[(size_t)(q0 + mf2*32 + st*16 + lr)*DMODEL
                                       + dh*256 + tt*32 + lg*8];
  // K fragments for iter 0 (single-buffered, refilled each iter)
  bf16x8 kreg[16];
  #pragma unroll
  for (int tt = 0; tt < 8; ++tt){
    int coff = dh*256 + tt*32 + lg*8;
    kreg[2*tt  ] = *(const bf16x8*)&Km[(size_t)(kbase + nf2*32 +      lr)*DMODEL + coff];
    kreg[2*tt+1] = *(const bf16x8*)&Km[(size_t)(kbase + nf2*32 + 16 + lr)*DMODEL + coff];
  }
  f32x4 acc[4][4] = {};
  if (tid < 64){ mls[tid] = -3.0e38f; lls[tid] = 0.0f; }
  __syncthreads();
  const float scale = 0.04419417382415922f;  // 1/sqrt(512)
  for (int j0 = 0; j0 < KEYS_PER; j0 += 64){
    // ---- QK: all operands in registers (zero memory stalls) ----
    f32x4 s00 = {}, s01 = {}, s10 = {}, s11 = {};
    #pragma unroll
    for (int tt = 0; tt < 8; ++tt){
      s00 = mfma16x16x32(qf[0][tt], kreg[2*tt  ], s00);
      s10 = mfma16x16x32(qf[1][tt], kreg[2*tt  ], s10);
      s01 = mfma16x16x32(qf[0][tt], kreg[2*tt+1], s01);
      s11 = mfma16x16x32(qf[1][tt], kreg[2*tt+1], s11);
    }
    // ---- refill kreg for next iter (lands during softmax/PV phases) ----
    {
      int jn = (j0 + 64 < KEYS_PER) ? j0 + 64 : 0;
      const __bf16* Kn = Km + (size_t)(kbase + jn) * DMODEL;
      #pragma unroll
      for (int tt = 0; tt < 8; ++tt){
        int coff = dh*256 + tt*32 + lg*8;
        kreg[2*tt  ] = *(const bf16x8*)&Kn[(size_t)(nf2*32 +      lr)*DMODEL + coff];
        kreg[2*tt+1] = *(const bf16x8*)&Kn[(size_t)(nf2*32 + 16 + lr)*DMODEL + coff];
      }
    }
    // ---- prefetch V frags (drain under S-write + sync1 + softmax) ----
    const __bf16* Vp = Vt + kbase + j0;
    bf16x8 vf[2][4];
    #pragma unroll
    for (int kt = 0; kt < 2; ++kt)
      #pragma unroll
      for (int nfa = 0; nfa < 4; ++nfa)
        vf[kt][nfa] = *(const bf16x8*)&Vp[(size_t)(d0 + nfa*16 + lr)*N_TOK
                                          + kt*32 + lg*8];
    // ---- write partial S (swizzled) ----
    #pragma unroll
    for (int r = 0; r < 4; ++r){
      int rowA = mf2*32 +      lg*4 + r;
      int rowB = mf2*32 + 16 + lg*4 + r;
      int colA = nf2*32 + lr, colB = nf2*32 + 16 + lr;
      SP[dh*4096 + rowA*64 + (colA ^ ((rowA&7)<<2))] = s00[r];
      SP[dh*4096 + rowB*64 + (colA ^ ((rowB&7)<<2))] = s10[r];
      SP[dh*4096 + rowA*64 + (colB ^ ((rowA&7)<<2))] = s01[r];
      SP[dh*4096 + rowB*64 + (colB ^ ((rowB&7)<<2))] = s11[r];
    }
    __syncthreads();  // sync1
    // ---- softmax: 8 lanes per row ----
    {
      int row = tid >> 3, ci = tid & 7;
      int sw = (row & 7) << 2;
      f32x4 a0 = *(const f32x4*)&SP[       row*64 + ((ci*8    ) ^ sw)];
      f32x4 a1 = *(const f32x4*)&SP[       row*64 + ((ci*8 + 4) ^ sw)];
      f32x4 b0 = *(const f32x4*)&SP[4096 + row*64 + ((ci*8    ) ^ sw)];
      f32x4 b1 = *(const f32x4*)&SP[4096 + row*64 + ((ci*8 + 4) ^ sw)];
      float v0=(a0[0]+b0[0])*scale, v1=(a0[1]+b0[1])*scale;
      float v2=(a0[2]+b0[2])*scale, v3=(a0[3]+b0[3])*scale;
      float v4=(a1[0]+b1[0])*scale, v5=(a1[1]+b1[1])*scale;
      float v6=(a1[2]+b1[2])*scale, v7=(a1[3]+b1[3])*scale;
      float mx = fmaxf(fmaxf(fmaxf(v0,v1),fmaxf(v2,v3)),
                       fmaxf(fmaxf(v4,v5),fmaxf(v6,v7)));
      #pragma unroll
      for (int dl = 1; dl < 8; dl <<= 1) mx = fmaxf(mx, __shfl_xor(mx, dl));
      float mold = mls[row];
      float mnew = fmaxf(mold, mx);
      float fac  = __expf(mold - mnew);
      float p0=__expf(v0-mnew), p1=__expf(v1-mnew), p2=__expf(v2-mnew), p3=__expf(v3-mnew);
      float p4=__expf(v4-mnew), p5=__expf(v5-mnew), p6=__expf(v6-mnew), p7=__expf(v7-mnew);
      float sum = ((p0+p1)+(p2+p3)) + ((p4+p5)+(p6+p7));
      #pragma unroll
      for (int dl = 1; dl < 8; dl <<= 1) sum += __shfl_xor(sum, dl);
      bf16x8 pb;
      pb[0]=(__bf16)p0; pb[1]=(__bf16)p1; pb[2]=(__bf16)p2; pb[3]=(__bf16)p3;
      pb[4]=(__bf16)p4; pb[5]=(__bf16)p5; pb[6]=(__bf16)p6; pb[7]=(__bf16)p7;
      *(bf16x8*)&Pls[row*64 + ((ci*8) ^ ((row&7)<<3))] = pb;
      if (ci == 0){ mls[row] = mnew; lls[row] = lls[row]*fac + sum; fls[row] = fac; }
    }
    __syncthreads();  // sync2
    // ---- rescale acc ----
    float fr[4][4];
    #pragma unroll
    for (int st = 0; st < 4; ++st)
      #pragma unroll
      for (int r = 0; r < 4; ++r)
        fr[st][r] = fls[st*16 + lg*4 + r];
    #pragma unroll
    for (int st = 0; st < 4; ++st)
      #pragma unroll
      for (int nfa = 0; nfa < 4; ++nfa)
        #pragma unroll
        for (int r = 0; r < 4; ++r)
          acc[st][nfa][r] *= fr[st][r];
    // ---- PV: P from LDS (swz), V from regs ----
    #pragma unroll
    for (int kt = 0; kt < 2; ++kt){
      bf16x8 pf[4];
      #pragma unroll
      for (int st = 0; st < 4; ++st){
        int prow = st*16 + lr;
        pf[st] = *(const bf16x8*)&Pls[prow*64 + ((kt*32 + lg*8) ^ ((prow&7)<<3))];
      }
      #pragma unroll
      for (int st = 0; st < 4; ++st)
        #pragma unroll
        for (int nfa = 0; nfa < 4; ++nfa)
          acc[st][nfa] = mfma16x16x32(pf[st], vf[kt][nfa], acc[st][nfa]);
    }
  }
  // ---- epilogue: normalized partial + stats ----
  __bf16* Op = sp ? O1 : O0;
  #pragma unroll
  for (int st = 0; st < 4; ++st)
    #pragma unroll
    for (int r = 0; r < 4; ++r){
      int row = st*16 + lg*4 + r;
      float inv = 1.0f / lls[row];
      #pragma unroll
      for (int nfa = 0; nfa < 4; ++nfa)
        Op[(size_t)(q0 + row)*DMODEL + d0 + nfa*16 + lr] = (__bf16)(acc[st][nfa][r] * inv);
    }
  if (tid < 64){
    mA[sp*N_TOK + q0 + tid] = mls[tid];
    lA[sp*N_TOK + q0 + tid] = lls[tid];
  }
}

// ---------------- combine the two key-splits ----------------
__global__ __launch_bounds__(256) void k_combine(
    const __bf16* __restrict__ O0, const __bf16* __restrict__ O1,
    const float* __restrict__ mA, const float* __restrict__ lA,
    __bf16* __restrict__ ctx)
{
  int idx = blockIdx.x * 256 + threadIdx.x;       // 8192*64
  int row = idx >> 6, ch = idx & 63;
  float m0 = mA[row], m1 = mA[N_TOK + row];
  float l0 = lA[row], l1 = lA[N_TOK + row];
  float mm = fmaxf(m0, m1);
  float w0 = l0 * __expf(m0 - mm), w1 = l1 * __expf(m1 - mm);
  float inv = 1.0f / (w0 + w1);
  w0 *= inv; w1 *= inv;
  size_t off = (size_t)row * (DMODEL/8) + ch;
  bf16x8 c0 = ((const bf16x8*)O0)[off];
  bf16x8 c1 = ((const bf16x8*)O1)[off];
  bf16x8 o;
  #pragma unroll
  for (int i = 0; i < 8; ++i)
    o[i] = (__bf16)((float)c0[i]*w0 + (float)c1[i]*w1);
  ((bf16x8*)ctx)[off] = o;
}

// ---------------- MLP head ----------------
__global__ __launch_bounds__(256) void k_mlp(
    const __bf16* __restrict__ ctx, const __bf16* __restrict__ W1t,
    const float* __restrict__ b1, const float* __restrict__ W2,
    const float* __restrict__ b2, float* __restrict__ out)
{
  __shared__ __bf16 Als[64][512];
  __shared__ float  red[4][64];
  const int tid = threadIdx.x;
  const int w = tid >> 6, l = tid & 63;
  const int lr = l & 15, lg = l >> 4;
  const int m0 = blockIdx.x * 64;
  #pragma unroll
  for (int i = 0; i < 16; ++i){
    int row = w*16 + i;
    async_copy16((char*)&Als[0][0] + row*1024,
                 ctx + (size_t)(m0 + row)*DMODEL + l*8);
  }
  __syncthreads();
  f32x4 acc[4][4] = {};
  for (int t = 0; t < 16; ++t){
    bf16x8 af[4];
    #pragma unroll
    for (int mf2 = 0; mf2 < 4; ++mf2) af[mf2] = *(const bf16x8*)&Als[mf2*16 + lr][t*32 + lg*8];
    #pragma unroll
    for (int nf2 = 0; nf2 < 4; ++nf2){
      bf16x8 bfr = *(const bf16x8*)&W1t[(size_t)(w*64 + nf2*16 + lr)*DMODEL + t*32 + lg*8];
      #pragma unroll
      for (int mf2 = 0; mf2 < 4; ++mf2)
        acc[mf2][nf2] = mfma16x16x32(af[mf2], bfr, acc[mf2][nf2]);
    }
  }
  float part[4][4] = {};
  #pragma unroll
  for (int nf2 = 0; nf2 < 4; ++nf2){
    int col = w*64 + nf2*16 + lr;
    float bb = b1[col], w2v = W2[col];
    #pragma unroll
    for (int mf2 = 0; mf2 < 4; ++mf2)
      #pragma unroll
      for (int r = 0; r < 4; ++r){
        float h = acc[mf2][nf2][r] + bb;
        h = h > 0.0f ? h : 0.0f;
        part[mf2][r] += h * w2v;
      }
  }
  #pragma unroll
  for (int mf2 = 0; mf2 < 4; ++mf2)
    #pragma unroll
    for (int r = 0; r < 4; ++r)
      #pragma unroll
      for (int dl = 1; dl < 16; dl <<= 1)
        part[mf2][r] += __shfl_xor(part[mf2][r], dl);
  if (lr == 0){
    #pragma unroll
    for (int mf2 = 0; mf2 < 4; ++mf2)
      #pragma unroll
      for (int r = 0; r < 4; ++r)
        red[w][mf2*16 + lg*4 + r] = part[mf2][r];
  }
  __syncthreads();
  if (tid < 64)
    out[m0 + tid] = red[0][tid] + red[1][tid] + red[2][tid] + red[3][tid] + b2[0];
}

// ---------------- launcher ----------------
extern "C" void kernel_launch(void* const* d_in, const int* in_sizes, int n_in,
                              void* d_out, int out_size, void* d_ws, size_t ws_size,
                              hipStream_t stream)
{
  const float* x  = (const float*)d_in[0];
  const float* Wq = (const float*)d_in[1];
  const float* bq = (const float*)d_in[2];
  const float* Wk = (const float*)d_in[3];
  const float* bk = (const float*)d_in[4];
  const float* Wv = (const float*)d_in[5];
  const float* bv = (const float*)d_in[6];
  const float* W1 = (const float*)d_in[7];
  const float* b1 = (const float*)d_in[8];
  const float* W2 = (const float*)d_in[9];
  const float* b2 = (const float*)d_in[10];
  float* out = (float*)d_out;
  char* ws = (char*)d_ws;
  __bf16* xb   = (__bf16*)(ws + 0);          // x bf16 (dead after GEMMs)
  __bf16* qb   = (__bf16*)(ws + 16777216);
  __bf16* kb   = (__bf16*)(ws + 25165824);
  __bf16* vtb  = (__bf16*)(ws + 33554432);
  __bf16* ctxb = (__bf16*)(ws + 41943040);
  __bf16* wqt  = (__bf16*)(ws + 50331648);
  __bf16* wkt  = (__bf16*)(ws + 51380224);
  __bf16* wvt  = (__bf16*)(ws + 52428800);
  __bf16* w1t  = (__bf16*)(ws + 53477376);
  // split-attention partials reuse the dead xb region
  __bf16* O1   = (__bf16*)(ws + 0);          // 8.39 MB
  float*  mA   = (float*)(ws + 8388608);
  float*  lA   = (float*)(ws + 8454144);

  k_cvt<<<2048, 256, 0, stream>>>(x, xb, N_TOK*INDIM/4);
  k_tcvt<<<512, 256, 0, stream>>>(Wq, wqt, INDIM, DMODEL);
  k_tcvt<<<512, 256, 0, stream>>>(Wk, wkt, INDIM, DMODEL);
  k_tcvt<<<512, 256, 0, stream>>>(Wv, wvt, INDIM, DMODEL);
  k_tcvt<<<256, 256, 0, stream>>>(W1, w1t, DMODEL, DMODEL/2);

  k_gemm_bt<0><<<dim3(N_TOK/128, DMODEL/128), 256, 0, stream>>>(xb, wqt, bq, qb, N_TOK, DMODEL, INDIM);
  k_gemm_bt<0><<<dim3(N_TOK/128, DMODEL/128), 256, 0, stream>>>(xb, wkt, bk, kb, N_TOK, DMODEL, INDIM);
  k_gemm_bt<1><<<dim3(DMODEL/128, N_TOK/128), 256, 0, stream>>>(wvt, xb, bv, vtb, DMODEL, N_TOK, INDIM);

  k_flash<<<dim3(N_TOK/64, SPLIT), 512, 0, stream>>>(qb, kb, vtb, ctxb, O1, mA, lA);
  k_combine<<<N_TOK*64/256, 256, 0, stream>>>(ctxb, O1, mA, lA, ctxb);
  k_mlp<<<N_TOK/64, 256, 0, stream>>>(ctxb, w1t, b1, W2, b2, out);

  (void)in_sizes; (void)n_in; (void)out_size; (void)ws_size;
}

// Round 11
// 416.007 us; speedup vs baseline: 2.1003x; 2.1003x over previous
//
#include <hip/hip_runtime.h>
#include <hip/hip_bf16.h>
#include <cstdint>
#include <cstddef>

typedef float  f32x4  __attribute__((ext_vector_type(4)));
typedef __bf16 bf16x8 __attribute__((ext_vector_type(8)));
typedef __bf16 bf16x4 __attribute__((ext_vector_type(4)));

#define N_TOK  8192
#define INDIM  1024
#define DMODEL 512
#define NHALF  4096   // key-split half for P materialization

__device__ __forceinline__ f32x4 mfma16x16x32(bf16x8 a, bf16x8 b, f32x4 c){
  return __builtin_amdgcn_mfma_f32_16x16x32_bf16(a, b, c, 0, 0, 0);
}

__device__ __forceinline__ void async_copy16(void* lds, const void* g){
  __builtin_amdgcn_global_load_lds((__attribute__((address_space(1))) void*)g,
                                   (__attribute__((address_space(3))) void*)lds,
                                   16, 0, 0);
}

// ---------------- convert / transpose ----------------
__global__ void k_cvt(const float* __restrict__ in, __bf16* __restrict__ out, int n4){
  int stride = gridDim.x * blockDim.x;
  for (int i = blockIdx.x * blockDim.x + threadIdx.x; i < n4; i += stride){
    f32x4 v = ((const f32x4*)in)[i];
    bf16x4 o;
    o[0]=(__bf16)v[0]; o[1]=(__bf16)v[1]; o[2]=(__bf16)v[2]; o[3]=(__bf16)v[3];
    ((bf16x4*)out)[i] = o;
  }
}

__global__ void k_tcvt(const float* __restrict__ W, __bf16* __restrict__ Wt, int Kd, int Nd){
  int total = Kd * Nd;
  int stride = gridDim.x * blockDim.x;
  for (int i = blockIdx.x * blockDim.x + threadIdx.x; i < total; i += stride){
    int k = i / Nd, n = i - k * Nd;
    Wt[(size_t)n * Kd + k] = (__bf16)W[i];
  }
}

// ---------------- generalized GEMM: C[M,N] = A[M,K] @ Bt[N,K]^T ----------------
// m97 structure: 128x128 tile, 4 waves, BK=32, global_load_lds staging.
// EPI: 0 = +bias[col]; 1 = +bias[row]; 2 = exp(scale*acc); 3 = plain.
template<int EPI>
__global__ __launch_bounds__(256) void k_gemm(
    const __bf16* __restrict__ A, const __bf16* __restrict__ Bt,
    const float* __restrict__ bias, __bf16* __restrict__ C,
    int M, int N, int K, int lda, int ldb, int ldc, float scale)
{
  __shared__ __bf16 Als[128][32];
  __shared__ __bf16 Bls[128][32];
  const int tid = threadIdx.x;
  const int w = tid >> 6, l = tid & 63;
  const int lr = l & 15, lg = l >> 4;
  const int wr = w >> 1, wc = w & 1;
  const int m0 = blockIdx.x * 128, n0 = blockIdx.y * 128;
  const int srow = l >> 2;
  const int skof = (l & 3) * 8;
  f32x4 acc[4][4] = {};
  for (int k0 = 0; k0 < K; k0 += 32){
    #pragma unroll
    for (int i = 0; i < 2; ++i){
      int c = i * 4 + w;
      async_copy16((char*)&Als[0][0] + c * 1024,
                   A  + (size_t)(m0 + c*16 + srow) * lda + k0 + skof);
      async_copy16((char*)&Bls[0][0] + c * 1024,
                   Bt + (size_t)(n0 + c*16 + srow) * ldb + k0 + skof);
    }
    __syncthreads();
    bf16x8 af[4], bfv[4];
    #pragma unroll
    for (int mf = 0; mf < 4; ++mf) af[mf]  = *(const bf16x8*)&Als[wr*64 + mf*16 + lr][lg*8];
    #pragma unroll
    for (int nf = 0; nf < 4; ++nf) bfv[nf] = *(const bf16x8*)&Bls[wc*64 + nf*16 + lr][lg*8];
    #pragma unroll
    for (int mf = 0; mf < 4; ++mf)
      #pragma unroll
      for (int nf = 0; nf < 4; ++nf)
        acc[mf][nf] = mfma16x16x32(af[mf], bfv[nf], acc[mf][nf]);
    __syncthreads();
  }
  #pragma unroll
  for (int mf = 0; mf < 4; ++mf)
    #pragma unroll
    for (int nf = 0; nf < 4; ++nf)
      #pragma unroll
      for (int r = 0; r < 4; ++r){
        int row = m0 + wr*64 + mf*16 + lg*4 + r;
        int col = n0 + wc*64 + nf*16 + lr;
        float v = acc[mf][nf][r];
        if (EPI == 0) v += bias[col];
        if (EPI == 1) v += bias[row];
        if (EPI == 2) v = __expf(v * scale);
        C[(size_t)row * ldc + col] = (__bf16)v;
      }
}

// ---------------- row sums of P half (bf16-consistent) ----------------
// grid 2048 x 256: wave w sums row bid*4+w of P[8192][4096]; rs += (h? prev:0)
template<int H>
__global__ __launch_bounds__(256) void k_rowsum(
    const __bf16* __restrict__ P, float* __restrict__ rs)
{
  const int w = threadIdx.x >> 6, l = threadIdx.x & 63;
  const int row = blockIdx.x * 4 + w;
  const __bf16* p = P + (size_t)row * NHALF;
  float s = 0.0f;
  #pragma unroll
  for (int i = 0; i < 8; ++i){
    bf16x8 v = *(const bf16x8*)&p[i*512 + l*8];
    #pragma unroll
    for (int j = 0; j < 8; ++j) s += (float)v[j];
  }
  #pragma unroll
  for (int dl = 1; dl < 64; dl <<= 1) s += __shfl_xor(s, dl);
  if (l == 0) rs[row] = (H ? rs[row] : 0.0f) + s;
}

// ---------------- ctx = (ctx0 + ctx1) / rs ----------------
__global__ __launch_bounds__(256) void k_addctx(
    const __bf16* __restrict__ c0p, const __bf16* __restrict__ c1p,
    const float* __restrict__ rs, __bf16* __restrict__ ctx)
{
  int idx = blockIdx.x * 256 + threadIdx.x;   // 8192*512/8
  int row = idx >> 6;
  float inv = 1.0f / rs[row];
  bf16x8 a = ((const bf16x8*)c0p)[idx];
  bf16x8 b = ((const bf16x8*)c1p)[idx];
  bf16x8 o;
  #pragma unroll
  for (int i = 0; i < 8; ++i)
    o[i] = (__bf16)(((float)a[i] + (float)b[i]) * inv);
  ((bf16x8*)ctx)[idx] = o;
}

// ---------------- MLP head ----------------
__global__ __launch_bounds__(256) void k_mlp(
    const __bf16* __restrict__ ctx, const __bf16* __restrict__ W1t,
    const float* __restrict__ b1, const float* __restrict__ W2,
    const float* __restrict__ b2, float* __restrict__ out)
{
  __shared__ __bf16 Als[64][512];
  __shared__ float  red[4][64];
  const int tid = threadIdx.x;
  const int w = tid >> 6, l = tid & 63;
  const int lr = l & 15, lg = l >> 4;
  const int m0 = blockIdx.x * 64;
  #pragma unroll
  for (int i = 0; i < 16; ++i){
    int row = w*16 + i;
    async_copy16((char*)&Als[0][0] + row*1024,
                 ctx + (size_t)(m0 + row)*DMODEL + l*8);
  }
  __syncthreads();
  f32x4 acc[4][4] = {};
  for (int t = 0; t < 16; ++t){
    bf16x8 af[4];
    #pragma unroll
    for (int mf2 = 0; mf2 < 4; ++mf2) af[mf2] = *(const bf16x8*)&Als[mf2*16 + lr][t*32 + lg*8];
    #pragma unroll
    for (int nf2 = 0; nf2 < 4; ++nf2){
      bf16x8 bfr = *(const bf16x8*)&W1t[(size_t)(w*64 + nf2*16 + lr)*DMODEL + t*32 + lg*8];
      #pragma unroll
      for (int mf2 = 0; mf2 < 4; ++mf2)
        acc[mf2][nf2] = mfma16x16x32(af[mf2], bfr, acc[mf2][nf2]);
    }
  }
  float part[4][4] = {};
  #pragma unroll
  for (int nf2 = 0; nf2 < 4; ++nf2){
    int col = w*64 + nf2*16 + lr;
    float bb = b1[col], w2v = W2[col];
    #pragma unroll
    for (int mf2 = 0; mf2 < 4; ++mf2)
      #pragma unroll
      for (int r = 0; r < 4; ++r){
        float h = acc[mf2][nf2][r] + bb;
        h = h > 0.0f ? h : 0.0f;
        part[mf2][r] += h * w2v;
      }
  }
  #pragma unroll
  for (int mf2 = 0; mf2 < 4; ++mf2)
    #pragma unroll
    for (int r = 0; r < 4; ++r)
      #pragma unroll
      for (int dl = 1; dl < 16; dl <<= 1)
        part[mf2][r] += __shfl_xor(part[mf2][r], dl);
  if (lr == 0){
    #pragma unroll
    for (int mf2 = 0; mf2 < 4; ++mf2)
      #pragma unroll
      for (int r = 0; r < 4; ++r)
        red[w][mf2*16 + lg*4 + r] = part[mf2][r];
  }
  __syncthreads();
  if (tid < 64)
    out[m0 + tid] = red[0][tid] + red[1][tid] + red[2][tid] + red[3][tid] + b2[0];
}

// ---------------- launcher ----------------
extern "C" void kernel_launch(void* const* d_in, const int* in_sizes, int n_in,
                              void* d_out, int out_size, void* d_ws, size_t ws_size,
                              hipStream_t stream)
{
  const float* x  = (const float*)d_in[0];
  const float* Wq = (const float*)d_in[1];
  const float* bq = (const float*)d_in[2];
  const float* Wk = (const float*)d_in[3];
  const float* bk = (const float*)d_in[4];
  const float* Wv = (const float*)d_in[5];
  const float* bv = (const float*)d_in[6];
  const float* W1 = (const float*)d_in[7];
  const float* b1 = (const float*)d_in[8];
  const float* W2 = (const float*)d_in[9];
  const float* b2 = (const float*)d_in[10];
  float* out = (float*)d_out;
  char* ws = (char*)d_ws;
  // layout (ws_size >= 127 MB verified in R7 by the NS=8 path running)
  __bf16* xb   = (__bf16*)(ws + 0);          // 16 MB (dead after QKV GEMMs)
  __bf16* qb   = (__bf16*)(ws + 16777216);   // 8 MB
  __bf16* kb   = (__bf16*)(ws + 25165824);   // 8 MB
  __bf16* vtb  = (__bf16*)(ws + 33554432);   // 8 MB  V^T [512][8192]
  __bf16* ctx0 = (__bf16*)(ws + 41943040);   // 8 MB  (also final ctx)
  __bf16* wqt  = (__bf16*)(ws + 50331648);
  __bf16* wkt  = (__bf16*)(ws + 51380224);
  __bf16* wvt  = (__bf16*)(ws + 52428800);
  __bf16* w1t  = (__bf16*)(ws + 53477376);   // ends 53739520
  float*  rs   = (float*)(ws + 57671680);    // 32 KB
  __bf16* Ph   = (__bf16*)(ws + 58720256);   // 64 MB  P half [8192][4096]
  __bf16* ctx1 = (__bf16*)(ws + 0);          // reuse dead xb region

  k_cvt<<<2048, 256, 0, stream>>>(x, xb, N_TOK*INDIM/4);
  k_tcvt<<<512, 256, 0, stream>>>(Wq, wqt, INDIM, DMODEL);
  k_tcvt<<<512, 256, 0, stream>>>(Wk, wkt, INDIM, DMODEL);
  k_tcvt<<<512, 256, 0, stream>>>(Wv, wvt, INDIM, DMODEL);
  k_tcvt<<<256, 256, 0, stream>>>(W1, w1t, DMODEL, DMODEL/2);

  // QKV projections
  k_gemm<0><<<dim3(64, 4), 256, 0, stream>>>(xb, wqt, bq, qb,
      N_TOK, DMODEL, INDIM, INDIM, INDIM, DMODEL, 0.f);
  k_gemm<0><<<dim3(64, 4), 256, 0, stream>>>(xb, wkt, bk, kb,
      N_TOK, DMODEL, INDIM, INDIM, INDIM, DMODEL, 0.f);
  k_gemm<1><<<dim3(4, 64), 256, 0, stream>>>(wvt, xb, bv, vtb,
      DMODEL, N_TOK, INDIM, INDIM, INDIM, N_TOK, 0.f);

  const float scale = 0.04419417382415922f;  // 1/sqrt(512)
  // ---- attention as two GEMM passes per key-half ----
  // h = 0
  k_gemm<2><<<dim3(64, 32), 256, 0, stream>>>(qb, kb, nullptr, Ph,
      N_TOK, NHALF, DMODEL, DMODEL, DMODEL, NHALF, scale);
  k_rowsum<0><<<2048, 256, 0, stream>>>(Ph, rs);
  k_gemm<3><<<dim3(64, 4), 256, 0, stream>>>(Ph, vtb, nullptr, ctx0,
      N_TOK, DMODEL, NHALF, NHALF, N_TOK, DMODEL, 0.f);
  // h = 1
  k_gemm<2><<<dim3(64, 32), 256, 0, stream>>>(qb, kb + (size_t)NHALF*DMODEL, nullptr, Ph,
      N_TOK, NHALF, DMODEL, DMODEL, DMODEL, NHALF, scale);
  k_rowsum<1><<<2048, 256, 0, stream>>>(Ph, rs);
  k_gemm<3><<<dim3(64, 4), 256, 0, stream>>>(Ph, vtb + NHALF, nullptr, ctx1,
      N_TOK, DMODEL, NHALF, NHALF, N_TOK, DMODEL, 0.f);

  // ctx = (ctx0 + ctx1) / rs   (in place into ctx0)
  k_addctx<<<N_TOK*DMODEL/8/256, 256, 0, stream>>>(ctx0, ctx1, rs, ctx0);
  k_mlp<<<N_TOK/64, 256, 0, stream>>>(ctx0, w1t, b1, W2, b2, out);

  (void)in_sizes; (void)n_in; (void)out_size; (void)ws_size;
}

// Round 12
// 345.772 us; speedup vs baseline: 2.5269x; 1.2031x over previous
//
#include <hip/hip_runtime.h>
#include <hip/hip_bf16.h>
#include <cstdint>
#include <cstddef>

typedef float  f32x4  __attribute__((ext_vector_type(4)));
typedef __bf16 bf16x8 __attribute__((ext_vector_type(8)));
typedef __bf16 bf16x4 __attribute__((ext_vector_type(4)));

#define N_TOK  8192
#define INDIM  1024
#define DMODEL 512
#define NHALF  4096   // key-split half for P materialization

__device__ __forceinline__ f32x4 mfma16x16x32(bf16x8 a, bf16x8 b, f32x4 c){
  return __builtin_amdgcn_mfma_f32_16x16x32_bf16(a, b, c, 0, 0, 0);
}

__device__ __forceinline__ void async_copy16(void* lds, const void* g){
  __builtin_amdgcn_global_load_lds((__attribute__((address_space(1))) void*)g,
                                   (__attribute__((address_space(3))) void*)lds,
                                   16, 0, 0);
}

// ---------------- convert / transpose / bias-concat ----------------
__global__ void k_cvt(const float* __restrict__ in, __bf16* __restrict__ out, int n4){
  int stride = gridDim.x * blockDim.x;
  for (int i = blockIdx.x * blockDim.x + threadIdx.x; i < n4; i += stride){
    f32x4 v = ((const f32x4*)in)[i];
    bf16x4 o;
    o[0]=(__bf16)v[0]; o[1]=(__bf16)v[1]; o[2]=(__bf16)v[2]; o[3]=(__bf16)v[3];
    ((bf16x4*)out)[i] = o;
  }
}

__global__ void k_tcvt(const float* __restrict__ W, __bf16* __restrict__ Wt, int Kd, int Nd){
  int total = Kd * Nd;
  int stride = gridDim.x * blockDim.x;
  for (int i = blockIdx.x * blockDim.x + threadIdx.x; i < total; i += stride){
    int k = i / Nd, n = i - k * Nd;
    Wt[(size_t)n * Kd + k] = (__bf16)W[i];
  }
}

__global__ void k_bias2(const float* __restrict__ a, const float* __restrict__ b,
                        float* __restrict__ o){
  int idx = blockIdx.x * 256 + threadIdx.x;   // 0..1023
  o[idx] = (idx < 512) ? a[idx] : b[idx - 512];
}

// ---------------- generalized GEMM: C[M,N] = A[M,K-chunk] @ Bt^T ------------
// m97 structure: 128x128 tile, 4 waves, BK=32, global_load_lds staging.
// blockIdx.z selects a K-chunk of length K (split-K); partial C written at
// C + z*M*ldc. EPI: 0 = +bias[col]; 1 = +bias[row]; 2 = exp(scale*acc); 3 = plain.
template<int EPI>
__global__ __launch_bounds__(256) void k_gemm(
    const __bf16* __restrict__ A, const __bf16* __restrict__ Bt,
    const float* __restrict__ bias, __bf16* __restrict__ C,
    int M, int N, int K, int lda, int ldb, int ldc, float scale)
{
  __shared__ __bf16 Als[128][32];
  __shared__ __bf16 Bls[128][32];
  const int tid = threadIdx.x;
  const int w = tid >> 6, l = tid & 63;
  const int lr = l & 15, lg = l >> 4;
  const int wr = w >> 1, wc = w & 1;
  const int m0 = blockIdx.x * 128, n0 = blockIdx.y * 128;
  const int kz = blockIdx.z * K;
  const int srow = l >> 2;
  const int skof = (l & 3) * 8;
  f32x4 acc[4][4] = {};
  for (int k0 = 0; k0 < K; k0 += 32){
    #pragma unroll
    for (int i = 0; i < 2; ++i){
      int c = i * 4 + w;
      async_copy16((char*)&Als[0][0] + c * 1024,
                   A  + (size_t)(m0 + c*16 + srow) * lda + kz + k0 + skof);
      async_copy16((char*)&Bls[0][0] + c * 1024,
                   Bt + (size_t)(n0 + c*16 + srow) * ldb + kz + k0 + skof);
    }
    __syncthreads();
    bf16x8 af[4], bfv[4];
    #pragma unroll
    for (int mf = 0; mf < 4; ++mf) af[mf]  = *(const bf16x8*)&Als[wr*64 + mf*16 + lr][lg*8];
    #pragma unroll
    for (int nf = 0; nf < 4; ++nf) bfv[nf] = *(const bf16x8*)&Bls[wc*64 + nf*16 + lr][lg*8];
    #pragma unroll
    for (int mf = 0; mf < 4; ++mf)
      #pragma unroll
      for (int nf = 0; nf < 4; ++nf)
        acc[mf][nf] = mfma16x16x32(af[mf], bfv[nf], acc[mf][nf]);
    __syncthreads();
  }
  __bf16* Cd = C + (size_t)blockIdx.z * (size_t)M * ldc;
  #pragma unroll
  for (int mf = 0; mf < 4; ++mf)
    #pragma unroll
    for (int nf = 0; nf < 4; ++nf)
      #pragma unroll
      for (int r = 0; r < 4; ++r){
        int row = m0 + wr*64 + mf*16 + lg*4 + r;
        int col = n0 + wc*64 + nf*16 + lr;
        float v = acc[mf][nf][r];
        if (EPI == 0) v += bias[col];
        if (EPI == 1) v += bias[row];
        if (EPI == 2) v = __expf(v * scale);
        Cd[(size_t)row * ldc + col] = (__bf16)v;
      }
}

// ---------------- row sums of P half (bf16-consistent) ----------------
template<int H>
__global__ __launch_bounds__(256) void k_rowsum(
    const __bf16* __restrict__ P, float* __restrict__ rs)
{
  const int w = threadIdx.x >> 6, l = threadIdx.x & 63;
  const int row = blockIdx.x * 4 + w;
  const __bf16* p = P + (size_t)row * NHALF;
  float s = 0.0f;
  #pragma unroll
  for (int i = 0; i < 8; ++i){
    bf16x8 v = *(const bf16x8*)&p[i*512 + l*8];
    #pragma unroll
    for (int j = 0; j < 8; ++j) s += (float)v[j];
  }
  #pragma unroll
  for (int dl = 1; dl < 64; dl <<= 1) s += __shfl_xor(s, dl);
  if (l == 0) rs[row] = (H ? rs[row] : 0.0f) + s;
}

// ---------------- ctx = (p00+p01+p10+p11) / rs ----------------
__global__ __launch_bounds__(256) void k_addctx4(
    const __bf16* __restrict__ p00, const __bf16* __restrict__ p01,
    const __bf16* __restrict__ p10, const __bf16* __restrict__ p11,
    const float* __restrict__ rs, __bf16* __restrict__ ctx)
{
  int idx = blockIdx.x * 256 + threadIdx.x;   // 8192*512/8
  int row = idx >> 6;
  float inv = 1.0f / rs[row];
  bf16x8 a = ((const bf16x8*)p00)[idx];
  bf16x8 b = ((const bf16x8*)p01)[idx];
  bf16x8 c = ((const bf16x8*)p10)[idx];
  bf16x8 d = ((const bf16x8*)p11)[idx];
  bf16x8 o;
  #pragma unroll
  for (int i = 0; i < 8; ++i)
    o[i] = (__bf16)((((float)a[i] + (float)b[i]) + ((float)c[i] + (float)d[i])) * inv);
  ((bf16x8*)ctx)[idx] = o;
}

// ---------------- MLP head ----------------
__global__ __launch_bounds__(256) void k_mlp(
    const __bf16* __restrict__ ctx, const __bf16* __restrict__ W1t,
    const float* __restrict__ b1, const float* __restrict__ W2,
    const float* __restrict__ b2, float* __restrict__ out)
{
  __shared__ __bf16 Als[64][512];
  __shared__ float  red[4][64];
  const int tid = threadIdx.x;
  const int w = tid >> 6, l = tid & 63;
  const int lr = l & 15, lg = l >> 4;
  const int m0 = blockIdx.x * 64;
  #pragma unroll
  for (int i = 0; i < 16; ++i){
    int row = w*16 + i;
    async_copy16((char*)&Als[0][0] + row*1024,
                 ctx + (size_t)(m0 + row)*DMODEL + l*8);
  }
  __syncthreads();
  f32x4 acc[4][4] = {};
  for (int t = 0; t < 16; ++t){
    bf16x8 af[4];
    #pragma unroll
    for (int mf2 = 0; mf2 < 4; ++mf2) af[mf2] = *(const bf16x8*)&Als[mf2*16 + lr][t*32 + lg*8];
    #pragma unroll
    for (int nf2 = 0; nf2 < 4; ++nf2){
      bf16x8 bfr = *(const bf16x8*)&W1t[(size_t)(w*64 + nf2*16 + lr)*DMODEL + t*32 + lg*8];
      #pragma unroll
      for (int mf2 = 0; mf2 < 4; ++mf2)
        acc[mf2][nf2] = mfma16x16x32(af[mf2], bfr, acc[mf2][nf2]);
    }
  }
  float part[4][4] = {};
  #pragma unroll
  for (int nf2 = 0; nf2 < 4; ++nf2){
    int col = w*64 + nf2*16 + lr;
    float bb = b1[col], w2v = W2[col];
    #pragma unroll
    for (int mf2 = 0; mf2 < 4; ++mf2)
      #pragma unroll
      for (int r = 0; r < 4; ++r){
        float h = acc[mf2][nf2][r] + bb;
        h = h > 0.0f ? h : 0.0f;
        part[mf2][r] += h * w2v;
      }
  }
  #pragma unroll
  for (int mf2 = 0; mf2 < 4; ++mf2)
    #pragma unroll
    for (int r = 0; r < 4; ++r)
      #pragma unroll
      for (int dl = 1; dl < 16; dl <<= 1)
        part[mf2][r] += __shfl_xor(part[mf2][r], dl);
  if (lr == 0){
    #pragma unroll
    for (int mf2 = 0; mf2 < 4; ++mf2)
      #pragma unroll
      for (int r = 0; r < 4; ++r)
        red[w][mf2*16 + lg*4 + r] = part[mf2][r];
  }
  __syncthreads();
  if (tid < 64)
    out[m0 + tid] = red[0][tid] + red[1][tid] + red[2][tid] + red[3][tid] + b2[0];
}

// ---------------- launcher ----------------
extern "C" void kernel_launch(void* const* d_in, const int* in_sizes, int n_in,
                              void* d_out, int out_size, void* d_ws, size_t ws_size,
                              hipStream_t stream)
{
  const float* x  = (const float*)d_in[0];
  const float* Wq = (const float*)d_in[1];
  const float* bq = (const float*)d_in[2];
  const float* Wk = (const float*)d_in[3];
  const float* bk = (const float*)d_in[4];
  const float* Wv = (const float*)d_in[5];
  const float* bv = (const float*)d_in[6];
  const float* W1 = (const float*)d_in[7];
  const float* b1 = (const float*)d_in[8];
  const float* W2 = (const float*)d_in[9];
  const float* b2 = (const float*)d_in[10];
  float* out = (float*)d_out;
  char* ws = (char*)d_ws;
  // workspace layout
  __bf16* xb   = (__bf16*)(ws + 0);          // 16 MB (dead after V GEMM)
  __bf16* qkb  = (__bf16*)(ws + 16777216);   // 16 MB [8192][1024]: row = [q|k] (dead after pexp1)
  __bf16* vtb  = (__bf16*)(ws + 33554432);   // 8 MB  V^T [512][8192]
  __bf16* ctx0 = (__bf16*)(ws + 41943040);   // 8 MB  final ctx
  __bf16* wqkt = (__bf16*)(ws + 50331648);   // 2 MB  [Wq^T ; Wk^T] contiguous
  __bf16* wvt  = (__bf16*)(ws + 52428800);   // 1 MB
  __bf16* w1t  = (__bf16*)(ws + 53477376);   // 0.25 MB
  float*  rs   = (float*)(ws + 57671680);    // 32 KB
  float*  bqk  = (float*)(ws + 57704448);    // 4 KB
  __bf16* Ph   = (__bf16*)(ws + 58720256);   // 64 MB  P half [8192][4096]
  // PV split-K partials (dead-region reuse)
  __bf16* p00  = (__bf16*)(ws + 0);          // xb region
  __bf16* p01  = (__bf16*)(ws + 8388608);
  __bf16* p10  = (__bf16*)(ws + 16777216);   // qkb region (dead after pexp1)
  __bf16* p11  = (__bf16*)(ws + 25165824);

  k_cvt<<<2048, 256, 0, stream>>>(x, xb, N_TOK*INDIM/4);
  k_tcvt<<<512, 256, 0, stream>>>(Wq, wqkt, INDIM, DMODEL);
  k_tcvt<<<512, 256, 0, stream>>>(Wk, wqkt + (size_t)DMODEL*INDIM, INDIM, DMODEL);
  k_tcvt<<<512, 256, 0, stream>>>(Wv, wvt, INDIM, DMODEL);
  k_tcvt<<<256, 256, 0, stream>>>(W1, w1t, DMODEL, DMODEL/2);
  k_bias2<<<4, 256, 0, stream>>>(bq, bk, bqk);

  // fused Q|K projection: [8192][1024] = xb @ [Wq|Wk] + [bq|bk]
  k_gemm<0><<<dim3(64, 8), 256, 0, stream>>>(xb, wqkt, bqk, qkb,
      N_TOK, 2*DMODEL, INDIM, INDIM, INDIM, 2*DMODEL, 0.f);
  // V^T = Wv^T @ x^T + bv (row bias)
  k_gemm<1><<<dim3(4, 64), 256, 0, stream>>>(wvt, xb, bv, vtb,
      DMODEL, N_TOK, INDIM, INDIM, INDIM, N_TOK, 0.f);

  const float scale = 0.04419417382415922f;  // 1/sqrt(512)
  const __bf16* Qm = qkb;            // lda 1024
  const __bf16* Km = qkb + DMODEL;   // ldb 1024
  // ---- half 0 ----
  k_gemm<2><<<dim3(64, 32), 256, 0, stream>>>(Qm, Km, nullptr, Ph,
      N_TOK, NHALF, DMODEL, 2*DMODEL, 2*DMODEL, NHALF, scale);
  k_rowsum<0><<<2048, 256, 0, stream>>>(Ph, rs);
  k_gemm<3><<<dim3(64, 4, 2), 256, 0, stream>>>(Ph, vtb, nullptr, p00,
      N_TOK, DMODEL, NHALF/2, NHALF, N_TOK, DMODEL, 0.f);
  // ---- half 1 ----
  k_gemm<2><<<dim3(64, 32), 256, 0, stream>>>(Qm, Km + (size_t)NHALF*2*DMODEL, nullptr, Ph,
      N_TOK, NHALF, DMODEL, 2*DMODEL, 2*DMODEL, NHALF, scale);
  k_rowsum<1><<<2048, 256, 0, stream>>>(Ph, rs);
  k_gemm<3><<<dim3(64, 4, 2), 256, 0, stream>>>(Ph, vtb + NHALF, nullptr, p10,
      N_TOK, DMODEL, NHALF/2, NHALF, N_TOK, DMODEL, 0.f);

  k_addctx4<<<N_TOK*DMODEL/8/256, 256, 0, stream>>>(p00, p01, p10, p11, rs, ctx0);
  k_mlp<<<N_TOK/64, 256, 0, stream>>>(ctx0, w1t, b1, W2, b2, out);

  (void)in_sizes; (void)n_in; (void)out_size; (void)ws_size;
}

// Round 13
// 341.649 us; speedup vs baseline: 2.5574x; 1.0121x over previous
//
#include <hip/hip_runtime.h>
#include <hip/hip_bf16.h>
#include <cstdint>
#include <cstddef>

typedef float  f32x4  __attribute__((ext_vector_type(4)));
typedef __bf16 bf16x8 __attribute__((ext_vector_type(8)));
typedef __bf16 bf16x4 __attribute__((ext_vector_type(4)));

#define N_TOK  8192
#define INDIM  1024
#define DMODEL 512
#define NHALF  4096   // key-split half for P materialization

__device__ __forceinline__ f32x4 mfma16x16x32(bf16x8 a, bf16x8 b, f32x4 c){
  return __builtin_amdgcn_mfma_f32_16x16x32_bf16(a, b, c, 0, 0, 0);
}

__device__ __forceinline__ void async_copy16(void* lds, const void* g){
  __builtin_amdgcn_global_load_lds((__attribute__((address_space(1))) void*)g,
                                   (__attribute__((address_space(3))) void*)lds,
                                   16, 0, 0);
}

// ---------------- convert / transpose / bias-concat ----------------
__global__ void k_cvt(const float* __restrict__ in, __bf16* __restrict__ out, int n4){
  int stride = gridDim.x * blockDim.x;
  for (int i = blockIdx.x * blockDim.x + threadIdx.x; i < n4; i += stride){
    f32x4 v = ((const f32x4*)in)[i];
    bf16x4 o;
    o[0]=(__bf16)v[0]; o[1]=(__bf16)v[1]; o[2]=(__bf16)v[2]; o[3]=(__bf16)v[3];
    ((bf16x4*)out)[i] = o;
  }
}

__global__ void k_tcvt(const float* __restrict__ W, __bf16* __restrict__ Wt, int Kd, int Nd){
  int total = Kd * Nd;
  int stride = gridDim.x * blockDim.x;
  for (int i = blockIdx.x * blockDim.x + threadIdx.x; i < total; i += stride){
    int k = i / Nd, n = i - k * Nd;
    Wt[(size_t)n * Kd + k] = (__bf16)W[i];
  }
}

__global__ void k_bias2(const float* __restrict__ a, const float* __restrict__ b,
                        float* __restrict__ o){
  int idx = blockIdx.x * 256 + threadIdx.x;   // 0..1023
  o[idx] = (idx < 512) ? a[idx] : b[idx - 512];
}

// ---------------- generalized GEMM: C[M,N] = A[M,K-chunk] @ Bt^T ------------
// m97 structure: 128x128 tile, 4 waves, BK=32, global_load_lds staging.
// EPI: 0 = +bias[col]; 2 = exp(scale*acc); 3 = plain.
// MAP: 0 = (x=m, y=n, z=K-chunk)
//      1 = linear grid 2048: xcd-chunked m (8 m-tiles/XCD, L2-resident A), n inner
//      2 = linear grid 512:  z = xcd>>2 (L2-resident B z-slice), n innermost
//          (4 consecutive blocks consume one A-tile from L2)
template<int EPI, int MAP>
__global__ __launch_bounds__(256) void k_gemm(
    const __bf16* __restrict__ A, const __bf16* __restrict__ Bt,
    const float* __restrict__ bias, __bf16* __restrict__ C,
    int M, int N, int K, int lda, int ldb, int ldc, float scale)
{
  __shared__ __bf16 Als[128][32];
  __shared__ __bf16 Bls[128][32];
  const int tid = threadIdx.x;
  const int w = tid >> 6, l = tid & 63;
  const int lr = l & 15, lg = l >> 4;
  const int wr = w >> 1, wc = w & 1;
  int m0, n0, kz, zsel;
  if (MAP == 0){
    m0 = blockIdx.x * 128; n0 = blockIdx.y * 128; zsel = blockIdx.z; kz = zsel * K;
  } else if (MAP == 1){
    int lin = blockIdx.x, xcd = lin & 7, idx = lin >> 3;
    m0 = (xcd*8 + (idx & 7)) * 128; n0 = (idx >> 3) * 128; zsel = 0; kz = 0;
  } else {
    int lin = blockIdx.x, xcd = lin & 7, i = lin >> 3;
    zsel = xcd >> 2; kz = zsel * K;
    m0 = ((xcd & 3)*16 + (i >> 2)) * 128; n0 = (i & 3) * 128;
  }
  const int srow = l >> 2;
  const int skof = (l & 3) * 8;
  f32x4 acc[4][4] = {};
  for (int k0 = 0; k0 < K; k0 += 32){
    #pragma unroll
    for (int i = 0; i < 2; ++i){
      int c = i * 4 + w;
      async_copy16((char*)&Als[0][0] + c * 1024,
                   A  + (size_t)(m0 + c*16 + srow) * lda + kz + k0 + skof);
      async_copy16((char*)&Bls[0][0] + c * 1024,
                   Bt + (size_t)(n0 + c*16 + srow) * ldb + kz + k0 + skof);
    }
    __syncthreads();
    bf16x8 af[4], bfv[4];
    #pragma unroll
    for (int mf = 0; mf < 4; ++mf) af[mf]  = *(const bf16x8*)&Als[wr*64 + mf*16 + lr][lg*8];
    #pragma unroll
    for (int nf = 0; nf < 4; ++nf) bfv[nf] = *(const bf16x8*)&Bls[wc*64 + nf*16 + lr][lg*8];
    #pragma unroll
    for (int mf = 0; mf < 4; ++mf)
      #pragma unroll
      for (int nf = 0; nf < 4; ++nf)
        acc[mf][nf] = mfma16x16x32(af[mf], bfv[nf], acc[mf][nf]);
    __syncthreads();
  }
  __bf16* Cd = C + (size_t)zsel * (size_t)M * ldc;
  #pragma unroll
  for (int mf = 0; mf < 4; ++mf)
    #pragma unroll
    for (int nf = 0; nf < 4; ++nf)
      #pragma unroll
      for (int r = 0; r < 4; ++r){
        int row = m0 + wr*64 + mf*16 + lg*4 + r;
        int col = n0 + wc*64 + nf*16 + lr;
        float v = acc[mf][nf][r];
        if (EPI == 0) v += bias[col];
        if (EPI == 2) v = __expf(v * scale);
        Cd[(size_t)row * ldc + col] = (__bf16)v;
      }
}

// ---------------- row sums of P half (bf16-consistent) ----------------
template<int H>
__global__ __launch_bounds__(256) void k_rowsum(
    const __bf16* __restrict__ P, float* __restrict__ rs)
{
  const int w = threadIdx.x >> 6, l = threadIdx.x & 63;
  const int row = blockIdx.x * 4 + w;
  const __bf16* p = P + (size_t)row * NHALF;
  float s = 0.0f;
  #pragma unroll
  for (int i = 0; i < 8; ++i){
    bf16x8 v = *(const bf16x8*)&p[i*512 + l*8];
    #pragma unroll
    for (int j = 0; j < 8; ++j) s += (float)v[j];
  }
  #pragma unroll
  for (int dl = 1; dl < 64; dl <<= 1) s += __shfl_xor(s, dl);
  if (l == 0) rs[row] = (H ? rs[row] : 0.0f) + s;
}

// ---------------- V-projection split-K combine: vtb = p0 + p1 + bv[row] -----
__global__ __launch_bounds__(256) void k_vcomb(
    const __bf16* __restrict__ p, const float* __restrict__ bv,
    __bf16* __restrict__ vtb)
{
  int idx = blockIdx.x * 256 + threadIdx.x;   // 512*8192/8
  int row = idx >> 10;                        // 1024 chunks per row
  float b = bv[row];
  bf16x8 a = ((const bf16x8*)p)[idx];
  bf16x8 c = ((const bf16x8*)(p + (size_t)DMODEL * N_TOK))[idx];
  bf16x8 o;
  #pragma unroll
  for (int i = 0; i < 8; ++i)
    o[i] = (__bf16)((float)a[i] + (float)c[i] + b);
  ((bf16x8*)vtb)[idx] = o;
}

// ---------------- ctx = (p00+p01+p10+p11) / rs ----------------
__global__ __launch_bounds__(256) void k_addctx4(
    const __bf16* __restrict__ p00, const __bf16* __restrict__ p01,
    const __bf16* __restrict__ p10, const __bf16* __restrict__ p11,
    const float* __restrict__ rs, __bf16* __restrict__ ctx)
{
  int idx = blockIdx.x * 256 + threadIdx.x;   // 8192*512/8
  int row = idx >> 6;
  float inv = 1.0f / rs[row];
  bf16x8 a = ((const bf16x8*)p00)[idx];
  bf16x8 b = ((const bf16x8*)p01)[idx];
  bf16x8 c = ((const bf16x8*)p10)[idx];
  bf16x8 d = ((const bf16x8*)p11)[idx];
  bf16x8 o;
  #pragma unroll
  for (int i = 0; i < 8; ++i)
    o[i] = (__bf16)((((float)a[i] + (float)b[i]) + ((float)c[i] + (float)d[i])) * inv);
  ((bf16x8*)ctx)[idx] = o;
}

// ---------------- MLP head ----------------
__global__ __launch_bounds__(256) void k_mlp(
    const __bf16* __restrict__ ctx, const __bf16* __restrict__ W1t,
    const float* __restrict__ b1, const float* __restrict__ W2,
    const float* __restrict__ b2, float* __restrict__ out)
{
  __shared__ __bf16 Als[64][512];
  __shared__ float  red[4][64];
  const int tid = threadIdx.x;
  const int w = tid >> 6, l = tid & 63;
  const int lr = l & 15, lg = l >> 4;
  const int m0 = blockIdx.x * 64;
  #pragma unroll
  for (int i = 0; i < 16; ++i){
    int row = w*16 + i;
    async_copy16((char*)&Als[0][0] + row*1024,
                 ctx + (size_t)(m0 + row)*DMODEL + l*8);
  }
  __syncthreads();
  f32x4 acc[4][4] = {};
  for (int t = 0; t < 16; ++t){
    bf16x8 af[4];
    #pragma unroll
    for (int mf2 = 0; mf2 < 4; ++mf2) af[mf2] = *(const bf16x8*)&Als[mf2*16 + lr][t*32 + lg*8];
    #pragma unroll
    for (int nf2 = 0; nf2 < 4; ++nf2){
      bf16x8 bfr = *(const bf16x8*)&W1t[(size_t)(w*64 + nf2*16 + lr)*DMODEL + t*32 + lg*8];
      #pragma unroll
      for (int mf2 = 0; mf2 < 4; ++mf2)
        acc[mf2][nf2] = mfma16x16x32(af[mf2], bfr, acc[mf2][nf2]);
    }
  }
  float part[4][4] = {};
  #pragma unroll
  for (int nf2 = 0; nf2 < 4; ++nf2){
    int col = w*64 + nf2*16 + lr;
    float bb = b1[col], w2v = W2[col];
    #pragma unroll
    for (int mf2 = 0; mf2 < 4; ++mf2)
      #pragma unroll
      for (int r = 0; r < 4; ++r){
        float h = acc[mf2][nf2][r] + bb;
        h = h > 0.0f ? h : 0.0f;
        part[mf2][r] += h * w2v;
      }
  }
  #pragma unroll
  for (int mf2 = 0; mf2 < 4; ++mf2)
    #pragma unroll
    for (int r = 0; r < 4; ++r)
      #pragma unroll
      for (int dl = 1; dl < 16; dl <<= 1)
        part[mf2][r] += __shfl_xor(part[mf2][r], dl);
  if (lr == 0){
    #pragma unroll
    for (int mf2 = 0; mf2 < 4; ++mf2)
      #pragma unroll
      for (int r = 0; r < 4; ++r)
        red[w][mf2*16 + lg*4 + r] = part[mf2][r];
  }
  __syncthreads();
  if (tid < 64)
    out[m0 + tid] = red[0][tid] + red[1][tid] + red[2][tid] + red[3][tid] + b2[0];
}

// ---------------- launcher ----------------
extern "C" void kernel_launch(void* const* d_in, const int* in_sizes, int n_in,
                              void* d_out, int out_size, void* d_ws, size_t ws_size,
                              hipStream_t stream)
{
  const float* x  = (const float*)d_in[0];
  const float* Wq = (const float*)d_in[1];
  const float* bq = (const float*)d_in[2];
  const float* Wk = (const float*)d_in[3];
  const float* bk = (const float*)d_in[4];
  const float* Wv = (const float*)d_in[5];
  const float* bv = (const float*)d_in[6];
  const float* W1 = (const float*)d_in[7];
  const float* b1 = (const float*)d_in[8];
  const float* W2 = (const float*)d_in[9];
  const float* b2 = (const float*)d_in[10];
  float* out = (float*)d_out;
  char* ws = (char*)d_ws;
  // workspace layout
  __bf16* xb   = (__bf16*)(ws + 0);          // 16 MB (dead after V GEMM)
  __bf16* qkb  = (__bf16*)(ws + 16777216);   // 16 MB [8192][1024] rows [q|k] (dead after pexp1)
  __bf16* vtb  = (__bf16*)(ws + 33554432);   // 8 MB  V^T [512][8192]
  __bf16* ctx0 = (__bf16*)(ws + 41943040);   // 8 MB  final ctx
  __bf16* wqkt = (__bf16*)(ws + 50331648);   // 2 MB  [Wq^T ; Wk^T]
  __bf16* wvt  = (__bf16*)(ws + 52428800);   // 1 MB
  __bf16* w1t  = (__bf16*)(ws + 53477376);   // 0.25 MB
  float*  rs   = (float*)(ws + 57671680);    // 32 KB
  float*  bqk  = (float*)(ws + 57704448);    // 4 KB
  __bf16* Ph   = (__bf16*)(ws + 58720256);   // 64 MB  P half [8192][4096]
  __bf16* vpp  = (__bf16*)(ws + 58720256);   // V-proj partials (Ph region, free early)
  // PV split-K partials (dead-region reuse)
  __bf16* p00  = (__bf16*)(ws + 0);          // xb region
  __bf16* p01  = (__bf16*)(ws + 8388608);
  __bf16* p10  = (__bf16*)(ws + 16777216);   // qkb region (dead after pexp1)
  __bf16* p11  = (__bf16*)(ws + 25165824);

  k_cvt<<<2048, 256, 0, stream>>>(x, xb, N_TOK*INDIM/4);
  k_tcvt<<<512, 256, 0, stream>>>(Wq, wqkt, INDIM, DMODEL);
  k_tcvt<<<512, 256, 0, stream>>>(Wk, wqkt + (size_t)DMODEL*INDIM, INDIM, DMODEL);
  k_tcvt<<<512, 256, 0, stream>>>(Wv, wvt, INDIM, DMODEL);
  k_tcvt<<<256, 256, 0, stream>>>(W1, w1t, DMODEL, DMODEL/2);
  k_bias2<<<4, 256, 0, stream>>>(bq, bk, bqk);

  // fused Q|K projection: [8192][1024] = xb @ [Wq|Wk] + [bq|bk]
  k_gemm<0,0><<<dim3(64, 8), 256, 0, stream>>>(xb, wqkt, bqk, qkb,
      N_TOK, 2*DMODEL, INDIM, INDIM, INDIM, 2*DMODEL, 0.f);
  // V^T = Wv^T @ x^T, split-K z=2 (partials), then +bv combine
  k_gemm<3,0><<<dim3(4, 64, 2), 256, 0, stream>>>(wvt, xb, nullptr, vpp,
      DMODEL, N_TOK, INDIM/2, INDIM, INDIM, N_TOK, 0.f);
  k_vcomb<<<DMODEL*N_TOK/8/256, 256, 0, stream>>>(vpp, bv, vtb);

  const float scale = 0.04419417382415922f;  // 1/sqrt(512)
  const __bf16* Qm = qkb;            // lda 1024
  const __bf16* Km = qkb + DMODEL;   // ldb 1024
  // ---- half 0 ----
  k_gemm<2,1><<<2048, 256, 0, stream>>>(Qm, Km, nullptr, Ph,
      N_TOK, NHALF, DMODEL, 2*DMODEL, 2*DMODEL, NHALF, scale);
  k_rowsum<0><<<2048, 256, 0, stream>>>(Ph, rs);
  k_gemm<3,2><<<512, 256, 0, stream>>>(Ph, vtb, nullptr, p00,
      N_TOK, DMODEL, NHALF/2, NHALF, N_TOK, DMODEL, 0.f);
  // ---- half 1 ----
  k_gemm<2,1><<<2048, 256, 0, stream>>>(Qm, Km + (size_t)NHALF*2*DMODEL, nullptr, Ph,
      N_TOK, NHALF, DMODEL, 2*DMODEL, 2*DMODEL, NHALF, scale);
  k_rowsum<1><<<2048, 256, 0, stream>>>(Ph, rs);
  k_gemm<3,2><<<512, 256, 0, stream>>>(Ph, vtb + NHALF, nullptr, p10,
      N_TOK, DMODEL, NHALF/2, NHALF, N_TOK, DMODEL, 0.f);

  k_addctx4<<<N_TOK*DMODEL/8/256, 256, 0, stream>>>(p00, p01, p10, p11, rs, ctx0);
  k_mlp<<<N_TOK/64, 256, 0, stream>>>(ctx0, w1t, b1, W2, b2, out);

  (void)in_sizes; (void)n_in; (void)out_size; (void)ws_size;
}